// Round 8
// baseline (221.313 us; speedup 1.0000x reference)
//
#include <hip/hip_runtime.h>
#include <math.h>

#define SEQ 16
#define HID 1024
#define G4 4096
#define LATENT 2048
#define NBLK 256          // 1 block per CU
#define SLOTW 16          // u32 per mailbox slot (64 B)

typedef float f4 __attribute__((ext_vector_type(4)));

__device__ __forceinline__ float sigmoidf_(float x) { return 1.f / (1.f + __expf(-x)); }
__device__ __forceinline__ float tanhf_(float x) { return 1.f - 2.f / (__expf(2.f * x) + 1.f); }
__device__ __forceinline__ float dot4e(f4 a, f4 b) {
    return a.x * b.x + a.y * b.y + a.z * b.z + a.w * b.w;
}

// ---------------------------------------------------------------------------
// Single fused kernel: xg0 prologue + two-layer recurrence.
// 256 blocks x 1024 threads; wave (u,g) owns gate g of hidden unit j=4*bid+u.
// MAILBOX barrier: slot[parity][bid] = {gen, h1[4](w1-4), h2[4](w5-8)} in one
// 64B line. Producer lanes (tid 0..3) store h into their own slot, wave-level
// s_waitcnt vmcnt(0) drains them, tid0 stores gen. Consumers: 256 lanes
// (waves 0-3) each poll ONE slot's gen, then read the h words from the same
// line into LDS. Even/odd slot sets by phase parity prevent overwrite races
// (a block's flag for barrier p+1 is stored only after its reads of set p-1
// completed). All cross-block traffic is relaxed agent-scope atomics: no
// cache-maintenance ops anywhere in the loop (R6/R7-proven primitives).
// ---------------------------------------------------------------------------
__global__ __launch_bounds__(1024, 4) void fused_all(
    const float* __restrict__ x,
    const float* __restrict__ w_ih0,
    const float* __restrict__ w_hh0,
    const float* __restrict__ b_ih0,
    const float* __restrict__ b_hh0,
    const float* __restrict__ w_ih1,
    const float* __restrict__ w_hh1,
    const float* __restrict__ b_ih1,
    const float* __restrict__ b_hh1,
    unsigned* __restrict__ arrive,
    float* __restrict__ out) {
    const int bid = blockIdx.x;
    const int tid = threadIdx.x;
    const int wv  = tid >> 6;   // 0..15
    const int ln  = tid & 63;
    const int u   = wv >> 2;    // unit-in-block 0..3
    const int g   = wv & 3;     // gate 0..3
    const int j   = bid * 4 + u;
    const int r   = g * HID + j;   // weight row, 0..4095

    __shared__ f4    xs4[SEQ * 128];   // 32 KB
    __shared__ float h1sf[HID];        // 4 KB
    __shared__ float h2sf[HID];        // 4 KB
    __shared__ float acts[4][4][2];    // [unit][gate][layer]

    // ---- issue recurrent-weight loads EARLY (latency hides under prologue) ----
    const f4* p0 = (const f4*)(w_hh0 + (size_t)r * HID);
    const f4* p1 = (const f4*)(w_ih1 + (size_t)r * HID);
    const f4* p2 = (const f4*)(w_hh1 + (size_t)r * HID);
    f4 wa0 = p0[ln], wa1 = p0[ln + 64], wa2 = p0[ln + 128], wa3 = p0[ln + 192];
    f4 wb0 = p1[ln], wb1 = p1[ln + 64], wb2 = p1[ln + 128], wb3 = p1[ln + 192];
    f4 wc0 = p2[ln], wc1 = p2[ln + 64], wc2 = p2[ln + 128], wc3 = p2[ln + 192];
    float bias1 = b_ih1[r] + b_hh1[r];

    // ---------------- prologue: xg0 for this wave's row r ----------------
    float acc[SEQ];
#pragma unroll
    for (int t = 0; t < SEQ; ++t) acc[t] = 0.f;

    const f4* xsrc = (const f4*)x;   // [16][512] f4
    for (int ch = 0; ch < 4; ++ch) {
        __syncthreads();
        {   // stage 2048 f4 (32 KB) with 1024 threads: 2 each
            const int i0 = tid, i1 = tid + 1024;
            xs4[i0] = xsrc[(i0 >> 7) * 512 + ch * 128 + (i0 & 127)];
            xs4[i1] = xsrc[(i1 >> 7) * 512 + ch * 128 + (i1 & 127)];
        }
        __syncthreads();
        const f4* wrow = (const f4*)(w_ih0 + (size_t)r * LATENT) + ch * 128;
        const f4 a0 = wrow[ln], a1 = wrow[ln + 64];
#pragma unroll
        for (int t = 0; t < SEQ; ++t)
            acc[t] += dot4e(a0, xs4[t * 128 + ln]) + dot4e(a1, xs4[t * 128 + ln + 64]);
    }
    float xgreg = 0.f;
    {
        const float bsum = b_ih0[r] + b_hh0[r];
#pragma unroll
        for (int t = 0; t < SEQ; ++t) {
            float v = acc[t];
#pragma unroll
            for (int off = 32; off; off >>= 1) v += __shfl_xor(v, off);
            if (ln == t) xgreg = v + bsum;
        }
    }

    // ---- pin weights AFTER prologue (forces VGPR residency, allows overlap) ----
    asm volatile("" : "+v"(wa0), "+v"(wa1), "+v"(wa2), "+v"(wa3));
    asm volatile("" : "+v"(wb0), "+v"(wb1), "+v"(wb2), "+v"(wb3));
    asm volatile("" : "+v"(wc0), "+v"(wc1), "+v"(wc2), "+v"(wc3));
    asm volatile("" : "+v"(xgreg), "+v"(bias1));

    float c0 = 0.f, c1 = 0.f;  // live in lanes tid 0..3

    // ---------------- phases ----------------
    for (int p = 0; p <= SEQ; ++p) {
        // ---- stage: poll mailbox set of phase p-1, pull h straight out ----
        if (p >= 1 && tid < NBLK) {
            const unsigned gen = (unsigned)p;
            const unsigned* slot = &arrive[(((p + 1) & 1) * NBLK + tid) * SLOTW];
            while ((int)(__hip_atomic_load(&slot[0], __ATOMIC_RELAXED,
                                           __HIP_MEMORY_SCOPE_AGENT) - gen) < 0)
                __builtin_amdgcn_s_sleep(1);
            __builtin_amdgcn_sched_barrier(0);  // keep data reads after poll
#pragma unroll
            for (int i = 0; i < 4; ++i)
                h1sf[tid * 4 + i] = __uint_as_float(
                    __hip_atomic_load(&slot[1 + i], __ATOMIC_RELAXED,
                                      __HIP_MEMORY_SCOPE_AGENT));
            if (p >= 2) {
#pragma unroll
                for (int i = 0; i < 4; ++i)
                    h2sf[tid * 4 + i] = __uint_as_float(
                        __hip_atomic_load(&slot[5 + i], __ATOMIC_RELAXED,
                                          __HIP_MEMORY_SCOPE_AGENT));
            }
        }
        __syncthreads();

        // ---- per-wave gate dots ----
        float d0 = 0.f, d1 = 0.f, d2 = 0.f;
        if (p >= 1) {
            const f4* h4 = (const f4*)h1sf;
            const f4 h0 = h4[ln], h1v = h4[ln + 64], h2v = h4[ln + 128], h3v = h4[ln + 192];
            d0 = dot4e(wa0, h0) + dot4e(wa1, h1v) + dot4e(wa2, h2v) + dot4e(wa3, h3v);
            d1 = dot4e(wb0, h0) + dot4e(wb1, h1v) + dot4e(wb2, h2v) + dot4e(wb3, h3v);
        }
        if (p >= 2) {
            const f4* h4 = (const f4*)h2sf;
            const f4 h0 = h4[ln], h1v = h4[ln + 64], h2v = h4[ln + 128], h3v = h4[ln + 192];
            d2 = dot4e(wc0, h0) + dot4e(wc1, h1v) + dot4e(wc2, h2v) + dot4e(wc3, h3v);
        }
#pragma unroll
        for (int off = 32; off; off >>= 1) {
            d0 += __shfl_xor(d0, off);
            d1 += __shfl_xor(d1, off);
            d2 += __shfl_xor(d2, off);
        }
        const float xp = __shfl(xgreg, p & 15);
        if (ln == 0) {
            if (p < SEQ)
                acts[u][g][0] = (g == 2) ? tanhf_(xp + d0) : sigmoidf_(xp + d0);
            if (p >= 1)
                acts[u][g][1] = (g == 2) ? tanhf_(d1 + bias1 + d2)
                                         : sigmoidf_(d1 + bias1 + d2);
        }
        __syncthreads();

        // ---- cell update: lanes tid 0..3 (wave 0), unit = tid ----
        float h2x = 0.f;
        if (tid < 4) {
            unsigned* myslot = &arrive[((p & 1) * NBLK + bid) * SLOTW];
            if (p < SEQ) {
                c0 = acts[tid][1][0] * c0 + acts[tid][0][0] * acts[tid][2][0];
                const float h1x = acts[tid][3][0] * tanhf_(c0);
                __hip_atomic_store(&myslot[1 + tid], __float_as_uint(h1x),
                                   __ATOMIC_RELAXED, __HIP_MEMORY_SCOPE_AGENT);
            }
            if (p >= 1) {
                c1 = acts[tid][1][1] * c1 + acts[tid][0][1] * acts[tid][2][1];
                h2x = acts[tid][3][1] * tanhf_(c1);
                if (p < SEQ)
                    __hip_atomic_store(&myslot[5 + tid], __float_as_uint(h2x),
                                       __ATOMIC_RELAXED, __HIP_MEMORY_SCOPE_AGENT);
            }
        }

        // ---- flag store: wave-level drain of the mailbox data stores ----
        if (p < SEQ) {
            asm volatile("s_waitcnt vmcnt(0)" ::: "memory");
            if (tid == 0)
                __hip_atomic_store(&arrive[((p & 1) * NBLK + bid) * SLOTW],
                                   (unsigned)(p + 1), __ATOMIC_RELAXED,
                                   __HIP_MEMORY_SCOPE_AGENT);
        }

        // ---- out[] writes AFTER the flag: off the critical path ----
        if (tid < 4 && p >= 1) {
            const int jj = bid * 4 + tid;
            out[HID + (p - 1) * HID + jj] = h2x;
            if (p == SEQ) out[jj] = h2x;
        }
    }
}

extern "C" void kernel_launch(void* const* d_in, const int* in_sizes, int n_in,
                              void* d_out, int out_size, void* d_ws, size_t ws_size,
                              hipStream_t stream) {
    const float* x     = (const float*)d_in[0];
    const float* w_ih0 = (const float*)d_in[1];
    const float* w_hh0 = (const float*)d_in[2];
    const float* b_ih0 = (const float*)d_in[3];
    const float* b_hh0 = (const float*)d_in[4];
    const float* w_ih1 = (const float*)d_in[5];
    const float* w_hh1 = (const float*)d_in[6];
    const float* b_ih1 = (const float*)d_in[7];
    const float* b_hh1 = (const float*)d_in[8];

    unsigned* arrive = (unsigned*)d_ws;   // 2 sets x 256 slots x 64 B = 32 KB
    float* out = (float*)d_out;

    fused_all<<<NBLK, 1024, 0, stream>>>(x, w_ih0, w_hh0, b_ih0, b_hh0,
                                         w_ih1, w_hh1, b_ih1, b_hh1,
                                         arrive, out);
}

// Round 9
// 190.486 us; speedup vs baseline: 1.1618x; 1.1618x over previous
//
#include <hip/hip_runtime.h>
#include <math.h>

#define SEQ 16
#define HID 1024
#define G4 4096
#define LATENT 2048
#define NBLK 256          // 1 block per CU
#define ASTRIDE 16        // arrive-slot stride in u32 (64 B)

typedef float f4 __attribute__((ext_vector_type(4)));

__device__ __forceinline__ float sigmoidf_(float x) { return 1.f / (1.f + __expf(-x)); }
__device__ __forceinline__ float tanhf_(float x) { return 1.f - 2.f / (__expf(2.f * x) + 1.f); }
__device__ __forceinline__ float dot4e(f4 a, f4 b) {
    return a.x * b.x + a.y * b.y + a.z * b.z + a.w * b.w;
}

// ---------------------------------------------------------------------------
// Single fused kernel: xg0 prologue + two-layer recurrence (R7 structure).
// 256 blocks x 1024 threads; wave (u,g) owns gate g of hidden unit j=4*bid+u.
// Cross-block traffic: separate h arrays (coalesced staging) + one padded
// flag/block; all relaxed agent-scope atomics, raw vmcnt(0) as release, no
// cache-maintenance ops in the loop (R6/R7-proven).
// R9 deltas vs R7: (1) barrier poll issues all 4 flag loads per iteration
// (joint test + s_sleep(2) backoff) instead of 4 sequential spin loops;
// (2) out[] stores moved after the flag store, off the vmcnt(0) drain path.
// ---------------------------------------------------------------------------
__global__ __launch_bounds__(1024, 4) void fused_all(
    const float* __restrict__ x,
    const float* __restrict__ w_ih0,
    const float* __restrict__ w_hh0,
    const float* __restrict__ b_ih0,
    const float* __restrict__ b_hh0,
    const float* __restrict__ w_ih1,
    const float* __restrict__ w_hh1,
    const float* __restrict__ b_ih1,
    const float* __restrict__ b_hh1,
    float* __restrict__ h1a, float* __restrict__ h1b,
    float* __restrict__ h2a, float* __restrict__ h2b,
    unsigned* __restrict__ arrive,
    float* __restrict__ out) {
    const int bid = blockIdx.x;
    const int tid = threadIdx.x;
    const int wv  = tid >> 6;   // 0..15
    const int ln  = tid & 63;
    const int u   = wv >> 2;    // unit-in-block 0..3
    const int g   = wv & 3;     // gate 0..3
    const int j   = bid * 4 + u;
    const int r   = g * HID + j;   // weight row, 0..4095

    __shared__ f4    xs4[SEQ * 128];   // 32 KB
    __shared__ float h1sf[HID];        // 4 KB
    __shared__ float h2sf[HID];        // 4 KB
    __shared__ float acts[4][4][2];    // [unit][gate][layer]

    // ---- issue recurrent-weight loads EARLY (latency hides under prologue) ----
    const f4* p0 = (const f4*)(w_hh0 + (size_t)r * HID);
    const f4* p1 = (const f4*)(w_ih1 + (size_t)r * HID);
    const f4* p2 = (const f4*)(w_hh1 + (size_t)r * HID);
    f4 wa0 = p0[ln], wa1 = p0[ln + 64], wa2 = p0[ln + 128], wa3 = p0[ln + 192];
    f4 wb0 = p1[ln], wb1 = p1[ln + 64], wb2 = p1[ln + 128], wb3 = p1[ln + 192];
    f4 wc0 = p2[ln], wc1 = p2[ln + 64], wc2 = p2[ln + 128], wc3 = p2[ln + 192];
    float bias1 = b_ih1[r] + b_hh1[r];

    // ---------------- prologue: xg0 for this wave's row r ----------------
    float acc[SEQ];
#pragma unroll
    for (int t = 0; t < SEQ; ++t) acc[t] = 0.f;

    const f4* xsrc = (const f4*)x;   // [16][512] f4
    for (int ch = 0; ch < 4; ++ch) {
        __syncthreads();
        {   // stage 2048 f4 (32 KB) with 1024 threads: 2 each
            const int i0 = tid, i1 = tid + 1024;
            xs4[i0] = xsrc[(i0 >> 7) * 512 + ch * 128 + (i0 & 127)];
            xs4[i1] = xsrc[(i1 >> 7) * 512 + ch * 128 + (i1 & 127)];
        }
        __syncthreads();
        const f4* wrow = (const f4*)(w_ih0 + (size_t)r * LATENT) + ch * 128;
        const f4 a0 = wrow[ln], a1 = wrow[ln + 64];
#pragma unroll
        for (int t = 0; t < SEQ; ++t)
            acc[t] += dot4e(a0, xs4[t * 128 + ln]) + dot4e(a1, xs4[t * 128 + ln + 64]);
    }
    float xgreg = 0.f;
    {
        const float bsum = b_ih0[r] + b_hh0[r];
#pragma unroll
        for (int t = 0; t < SEQ; ++t) {
            float v = acc[t];
#pragma unroll
            for (int off = 32; off; off >>= 1) v += __shfl_xor(v, off);
            if (ln == t) xgreg = v + bsum;
        }
    }

    // ---- pin weights AFTER prologue (forces VGPR residency, allows overlap) ----
    asm volatile("" : "+v"(wa0), "+v"(wa1), "+v"(wa2), "+v"(wa3));
    asm volatile("" : "+v"(wb0), "+v"(wb1), "+v"(wb2), "+v"(wb3));
    asm volatile("" : "+v"(wc0), "+v"(wc1), "+v"(wc2), "+v"(wc3));
    asm volatile("" : "+v"(xgreg), "+v"(bias1));

    float c0 = 0.f, c1 = 0.f;  // live in lanes tid 0..3

    // ---------------- phases ----------------
    for (int p = 0; p <= SEQ; ++p) {
        const float* h1r = (p & 1) ? h1a : h1b;
        const float* h2r = (p & 1) ? h2a : h2b;
        float* h1w = (p & 1) ? h1b : h1a;
        float* h2w = (p & 1) ? h2b : h2a;

        // ---- stage previous h into LDS (coalesced relaxed atomic loads) ----
        if (p >= 1)
            h1sf[tid] = __hip_atomic_load(&h1r[tid], __ATOMIC_RELAXED,
                                          __HIP_MEMORY_SCOPE_AGENT);
        if (p >= 2)
            h2sf[tid] = __hip_atomic_load(&h2r[tid], __ATOMIC_RELAXED,
                                          __HIP_MEMORY_SCOPE_AGENT);
        __syncthreads();

        // ---- per-wave gate dots ----
        float d0 = 0.f, d1 = 0.f, d2 = 0.f;
        if (p >= 1) {
            const f4* h4 = (const f4*)h1sf;
            const f4 h0 = h4[ln], h1v = h4[ln + 64], h2v = h4[ln + 128], h3v = h4[ln + 192];
            d0 = dot4e(wa0, h0) + dot4e(wa1, h1v) + dot4e(wa2, h2v) + dot4e(wa3, h3v);
            d1 = dot4e(wb0, h0) + dot4e(wb1, h1v) + dot4e(wb2, h2v) + dot4e(wb3, h3v);
        }
        if (p >= 2) {
            const f4* h4 = (const f4*)h2sf;
            const f4 h0 = h4[ln], h1v = h4[ln + 64], h2v = h4[ln + 128], h3v = h4[ln + 192];
            d2 = dot4e(wc0, h0) + dot4e(wc1, h1v) + dot4e(wc2, h2v) + dot4e(wc3, h3v);
        }
#pragma unroll
        for (int off = 32; off; off >>= 1) {
            d0 += __shfl_xor(d0, off);
            d1 += __shfl_xor(d1, off);
            d2 += __shfl_xor(d2, off);
        }
        const float xp = __shfl(xgreg, p & 15);
        if (ln == 0) {
            if (p < SEQ)
                acts[u][g][0] = (g == 2) ? tanhf_(xp + d0) : sigmoidf_(xp + d0);
            if (p >= 1)
                acts[u][g][1] = (g == 2) ? tanhf_(d1 + bias1 + d2)
                                         : sigmoidf_(d1 + bias1 + d2);
        }
        __syncthreads();

        // ---- cell update: lanes tid 0..3 (wave 0), unit = tid ----
        float h2x = 0.f;
        if (tid < 4) {
            const int jj = bid * 4 + tid;
            if (p < SEQ) {
                c0 = acts[tid][1][0] * c0 + acts[tid][0][0] * acts[tid][2][0];
                const float h1x = acts[tid][3][0] * tanhf_(c0);
                __hip_atomic_store(&h1w[jj], h1x, __ATOMIC_RELAXED,
                                   __HIP_MEMORY_SCOPE_AGENT);
            }
            if (p >= 1) {
                c1 = acts[tid][1][1] * c1 + acts[tid][0][1] * acts[tid][2][1];
                h2x = acts[tid][3][1] * tanhf_(c1);
                if (p < SEQ)
                    __hip_atomic_store(&h2w[jj], h2x, __ATOMIC_RELAXED,
                                       __HIP_MEMORY_SCOPE_AGENT);
            }
        }

        // ---- grid barrier: drain h-stores, set flag, parallel-poll all 256 ----
        if (p < SEQ) {
            const unsigned gen = (unsigned)(p + 1);
            asm volatile("s_waitcnt vmcnt(0)" ::: "memory");
            if (tid == 0)
                __hip_atomic_store(&arrive[bid * ASTRIDE], gen, __ATOMIC_RELAXED,
                                   __HIP_MEMORY_SCOPE_AGENT);
            if (wv == 0) {
                const unsigned* s0 = &arrive[(ln * 4 + 0) * ASTRIDE];
                const unsigned* s1 = &arrive[(ln * 4 + 1) * ASTRIDE];
                const unsigned* s2 = &arrive[(ln * 4 + 2) * ASTRIDE];
                const unsigned* s3 = &arrive[(ln * 4 + 3) * ASTRIDE];
                for (;;) {
                    // issue all 4 flag loads back-to-back: one LLC round trip
                    const unsigned v0 = __hip_atomic_load(s0, __ATOMIC_RELAXED,
                                                          __HIP_MEMORY_SCOPE_AGENT);
                    const unsigned v1 = __hip_atomic_load(s1, __ATOMIC_RELAXED,
                                                          __HIP_MEMORY_SCOPE_AGENT);
                    const unsigned v2 = __hip_atomic_load(s2, __ATOMIC_RELAXED,
                                                          __HIP_MEMORY_SCOPE_AGENT);
                    const unsigned v3 = __hip_atomic_load(s3, __ATOMIC_RELAXED,
                                                          __HIP_MEMORY_SCOPE_AGENT);
                    if (((int)(v0 - gen) >= 0) & ((int)(v1 - gen) >= 0) &
                        ((int)(v2 - gen) >= 0) & ((int)(v3 - gen) >= 0))
                        break;
                    __builtin_amdgcn_s_sleep(2);
                }
            }
            __syncthreads();
        }

        // ---- out[] writes AFTER the flag: off the release path ----
        if (tid < 4 && p >= 1) {
            const int jj = bid * 4 + tid;
            out[HID + (p - 1) * HID + jj] = h2x;
            if (p == SEQ) out[jj] = h2x;
        }
    }
}

extern "C" void kernel_launch(void* const* d_in, const int* in_sizes, int n_in,
                              void* d_out, int out_size, void* d_ws, size_t ws_size,
                              hipStream_t stream) {
    const float* x     = (const float*)d_in[0];
    const float* w_ih0 = (const float*)d_in[1];
    const float* w_hh0 = (const float*)d_in[2];
    const float* b_ih0 = (const float*)d_in[3];
    const float* b_hh0 = (const float*)d_in[4];
    const float* w_ih1 = (const float*)d_in[5];
    const float* w_hh1 = (const float*)d_in[6];
    const float* b_ih1 = (const float*)d_in[7];
    const float* b_hh1 = (const float*)d_in[8];

    float* h1a = (float*)d_ws;
    float* h1b = h1a + HID;
    float* h2a = h1b + HID;
    float* h2b = h2a + HID;
    unsigned* arrive = (unsigned*)(h2b + HID);  // 256*16 u32 = 16 KB
    float* out = (float*)d_out;

    fused_all<<<NBLK, 1024, 0, stream>>>(x, w_ih0, w_hh0, b_ih0, b_hh0,
                                         w_ih1, w_hh1, b_ih1, b_hh1,
                                         h1a, h1b, h2a, h2b, arrive, out);
}